// Round 10
// baseline (206.814 us; speedup 1.0000x reference)
//
#include <hip/hip_runtime.h>
#include <math.h>

#define NB 2
#define NT 4096
#define NC 512
#define NH 8
#define ND 64
#define N3C (3*NC)

typedef __attribute__((ext_vector_type(8))) __bf16 bf16x8;
typedef __attribute__((ext_vector_type(4))) __bf16 bf16x4;
typedef __attribute__((ext_vector_type(4))) float  f32x4;

// ---------------------------------------------------------------------------
// prep: W[K][N] fp32 -> Wt[N][K] bf16 for both weight matrices, one launch.
// blocks 0..191: Wqkv (24x8 tiles). blocks 192..255: Wproj (8x8 tiles).
// ---------------------------------------------------------------------------
__global__ __launch_bounds__(256) void prep_kernel(
    const float* __restrict__ Wqkv, const float* __restrict__ Wproj,
    __bf16* __restrict__ wqkvt, __bf16* __restrict__ wprojt)
{
    __shared__ float T[64][65];
    int id = blockIdx.x;
    const float* W; __bf16* Wt; int N, n0, k0;
    if (id < 192) { W = Wqkv;  Wt = wqkvt;  N = N3C; n0 = (id % 24) << 6; k0 = (id / 24) << 6; }
    else { id -= 192; W = Wproj; Wt = wprojt; N = NC;  n0 = (id & 7) << 6;  k0 = (id >> 3) << 6; }
    const int K = NC;

    const int tx = threadIdx.x & 15, ty = threadIdx.x >> 4;
#pragma unroll
    for (int i = 0; i < 4; ++i) {
        const int r = ty + (i << 4);
        float4 v = *(const float4*)(W + (size_t)(k0 + r) * N + n0 + (tx << 2));
        T[r][(tx << 2) + 0] = v.x;
        T[r][(tx << 2) + 1] = v.y;
        T[r][(tx << 2) + 2] = v.z;
        T[r][(tx << 2) + 3] = v.w;
    }
    __syncthreads();
#pragma unroll
    for (int i = 0; i < 4; ++i) {
        const int nr = ty + (i << 4);
        bf16x4 o;
        o[0] = (__bf16)T[(tx << 2) + 0][nr];
        o[1] = (__bf16)T[(tx << 2) + 1][nr];
        o[2] = (__bf16)T[(tx << 2) + 2][nr];
        o[3] = (__bf16)T[(tx << 2) + 3][nr];
        *(bf16x4*)(Wt + (size_t)(n0 + nr) * K + k0 + (tx << 2)) = o;
    }
}

// ---------------------------------------------------------------------------
// bf16 MFMA GEMM: C[M][N] = A[M][K] @ Bt[N][K]^T + bias[N]
// AF32: A is fp32 in global, converted to bf16 during LDS staging
// (bit-identical LDS contents to the old cvt-kernel path).
// ---------------------------------------------------------------------------
template<bool AF32>
__global__ __launch_bounds__(256) void gemm_bf16_kernel(
    const void* __restrict__ Aptr, const __bf16* __restrict__ Bt,
    const float* __restrict__ bias, void* __restrict__ Cout,
    int M, int N, int K, int out_bf16)
{
    __shared__ __bf16 As[128][40];
    __shared__ __bf16 Bs[128][40];

    const int tid  = threadIdx.x;
    const int w    = tid >> 6, lane = tid & 63;
    const int g    = lane >> 4, n = lane & 15;
    const int wr   = (w >> 1) << 6;
    const int wc   = (w & 1) << 6;
    const int m0   = blockIdx.y << 7, n0 = blockIdx.x << 7;

    const int sr = tid >> 1;
    const int sh = (tid & 1) << 4;
    const __bf16* ap_h = (const __bf16*)Aptr + (size_t)(m0 + sr) * K + sh;
    const float*  ap_f = (const float*) Aptr + (size_t)(m0 + sr) * K + sh;
    const __bf16* bp   = Bt + (size_t)(n0 + sr) * K + sh;

    f32x4 acc[4][4];
#pragma unroll
    for (int i = 0; i < 4; ++i)
#pragma unroll
        for (int j = 0; j < 4; ++j) acc[i][j] = (f32x4){0.f, 0.f, 0.f, 0.f};

    bf16x8 a0, a1;
    float4 f0, f1, f2, f3;
    if constexpr (AF32) {
        f0 = *(const float4*)(ap_f);
        f1 = *(const float4*)(ap_f + 4);
        f2 = *(const float4*)(ap_f + 8);
        f3 = *(const float4*)(ap_f + 12);
    } else {
        a0 = *(const bf16x8*)ap_h;
        a1 = *(const bf16x8*)(ap_h + 8);
    }
    bf16x8 b0 = *(const bf16x8*)bp;
    bf16x8 b1 = *(const bf16x8*)(bp + 8);

    const int ksteps = K >> 5;
    for (int ks = 0; ks < ksteps; ++ks) {
        __syncthreads();
        if constexpr (AF32) {
            bf16x8 c0, c1;
            c0[0] = (__bf16)f0.x; c0[1] = (__bf16)f0.y; c0[2] = (__bf16)f0.z; c0[3] = (__bf16)f0.w;
            c0[4] = (__bf16)f1.x; c0[5] = (__bf16)f1.y; c0[6] = (__bf16)f1.z; c0[7] = (__bf16)f1.w;
            c1[0] = (__bf16)f2.x; c1[1] = (__bf16)f2.y; c1[2] = (__bf16)f2.z; c1[3] = (__bf16)f2.w;
            c1[4] = (__bf16)f3.x; c1[5] = (__bf16)f3.y; c1[6] = (__bf16)f3.z; c1[7] = (__bf16)f3.w;
            *(bf16x8*)&As[sr][sh]     = c0;
            *(bf16x8*)&As[sr][sh + 8] = c1;
        } else {
            *(bf16x8*)&As[sr][sh]     = a0;
            *(bf16x8*)&As[sr][sh + 8] = a1;
        }
        *(bf16x8*)&Bs[sr][sh]     = b0;
        *(bf16x8*)&Bs[sr][sh + 8] = b1;
        __syncthreads();

        if (ks + 1 < ksteps) {
            const int ko = (ks + 1) << 5;
            if constexpr (AF32) {
                f0 = *(const float4*)(ap_f + ko);
                f1 = *(const float4*)(ap_f + ko + 4);
                f2 = *(const float4*)(ap_f + ko + 8);
                f3 = *(const float4*)(ap_f + ko + 12);
            } else {
                a0 = *(const bf16x8*)(ap_h + ko);
                a1 = *(const bf16x8*)(ap_h + ko + 8);
            }
            b0 = *(const bf16x8*)(bp + ko);
            b1 = *(const bf16x8*)(bp + ko + 8);
        }

        bf16x8 af[4], bf[4];
#pragma unroll
        for (int i = 0; i < 4; ++i) {
            af[i] = *(const bf16x8*)&As[wr + (i << 4) + n][g << 3];
            bf[i] = *(const bf16x8*)&Bs[wc + (i << 4) + n][g << 3];
        }
#pragma unroll
        for (int i = 0; i < 4; ++i)
#pragma unroll
            for (int j = 0; j < 4; ++j)
                acc[i][j] = __builtin_amdgcn_mfma_f32_16x16x32_bf16(af[i], bf[j], acc[i][j], 0, 0, 0);
    }

#pragma unroll
    for (int j = 0; j < 4; ++j) {
        const int colg = n0 + wc + (j << 4) + n;
        const float bb = bias[colg];
#pragma unroll
        for (int i = 0; i < 4; ++i) {
#pragma unroll
            for (int reg = 0; reg < 4; ++reg) {
                const int rowg = m0 + wr + (i << 4) + (g << 2) + reg;
                const float v = acc[i][j][reg] + bb;
                if (out_bf16)
                    ((__bf16*)Cout)[(size_t)rowg * N + colg] = (__bf16)v;
                else
                    ((float*)Cout)[(size_t)rowg * N + colg] = v;
            }
        }
    }
}

// ---------------------------------------------------------------------------
// Causal flash attention, bf16 MFMA, no-max softmax. R9 structure unchanged:
// 2D wave tiling (4 qg x 2 kh), per-half K/V reads, single K=32 PV MFMA,
// cross-wave reduction once per block, balanced qb swizzle.
// ---------------------------------------------------------------------------
__global__ __launch_bounds__(512) void attn_kernel(
    const __bf16* __restrict__ qkv, __bf16* __restrict__ out)
{
    __shared__ __align__(16) unsigned char SMEM[36352];
    __bf16 (*QPs)[72] = (__bf16(*)[72])SMEM;            // 128x72 bf16
    __bf16 (*Ks)[72]  = (__bf16(*)[72])(SMEM + 18432);  // 64x72  bf16
    __bf16 (*Vt)[68]  = (__bf16(*)[68])(SMEM + 27648);  // 64x68  bf16

    const int tid  = threadIdx.x;
    const int xi   = blockIdx.x;
    const int bh   = blockIdx.y;
    const int qb   = (bh < 8) ? (31 - xi) : xi;   // pair-balanced sizes per CU
    const int b    = bh >> 3, h = bh & 7;
    const int qr0  = qb << 7;
    const size_t base = (size_t)b * NT * N3C;
    const int col  = h * ND;

    const int w    = tid >> 6;
    const int lane = tid & 63;
    const int g    = lane >> 4;
    const int n    = lane & 15;
    const int qg   = w >> 1;
    const int kh   = w & 1;
    const int qrow0 = qg << 5;
    const int kcol0 = kh << 5;
    const int sw   = (g ^ (n >> 2)) << 3;

    const int kr = tid >> 3;
    const int kc = (tid & 7) << 3;
    const int vd = lane;
    const int vk = w << 2;

    const __bf16* kptr = qkv + base + NC + col + kc;
    const __bf16* vptr = qkv + base + 2 * NC + col + vd;

#pragma unroll
    for (int i = 0; i < 2; ++i) {
        const int r = kr + (i << 6);
        bf16x8 v = *(const bf16x8*)(qkv + base + (size_t)(qr0 + r) * N3C + col + kc);
        bf16x8 q;
#pragma unroll
        for (int j = 0; j < 8; ++j) q[j] = (__bf16)(0.125f * (float)v[j]);
        *(bf16x8*)&QPs[r][kc] = q;
    }
    __syncthreads();

    bf16x8 qf[2][2];
#pragma unroll
    for (int qt = 0; qt < 2; ++qt)
#pragma unroll
        for (int hh = 0; hh < 2; ++hh)
            qf[qt][hh] = *(const bf16x8*)&QPs[qrow0 + (qt << 4) + n][(hh << 5) + (g << 3)];

    bf16x8 ones;
#pragma unroll
    for (int j = 0; j < 8; ++j) ones[j] = (__bf16)1.0f;

    f32x4 O[2][4];
#pragma unroll
    for (int qt = 0; qt < 2; ++qt)
#pragma unroll
        for (int dt = 0; dt < 4; ++dt) O[qt][dt] = (f32x4){0.f, 0.f, 0.f, 0.f};
    f32x4 L[2] = {{0.f,0.f,0.f,0.f},{0.f,0.f,0.f,0.f}};

    bf16x8 kreg = *(const bf16x8*)(kptr + (size_t)kr * N3C);
    __bf16 vreg[8];
#pragma unroll
    for (int j = 0; j < 4; ++j) {
        vreg[j]     = vptr[(size_t)(vk + j) * N3C];
        vreg[4 + j] = vptr[(size_t)(vk + 32 + j) * N3C];
    }

    const int ntiles = (qb << 1) + 2;
    for (int jt = 0; jt < ntiles; ++jt) {
        __syncthreads();
        *(bf16x8*)&Ks[kr][kc] = kreg;
        {
            bf16x4 va, vb;
#pragma unroll
            for (int j = 0; j < 4; ++j) { va[j] = vreg[j]; vb[j] = vreg[4 + j]; }
            *(bf16x4*)&Vt[vd][vk]      = va;
            *(bf16x4*)&Vt[vd][vk + 32] = vb;
        }
        __syncthreads();

        if (jt + 1 < ntiles) {
            const int kr1 = (jt + 1) << 6;
            kreg = *(const bf16x8*)(kptr + (size_t)(kr1 + kr) * N3C);
#pragma unroll
            for (int j = 0; j < 4; ++j) {
                vreg[j]     = vptr[(size_t)(kr1 + vk + j) * N3C];
                vreg[4 + j] = vptr[(size_t)(kr1 + vk + 32 + j) * N3C];
            }
        }

        f32x4 S[2][2];
#pragma unroll
        for (int t = 0; t < 2; ++t) {
            const bf16x8 k0 = *(const bf16x8*)&Ks[kcol0 + (t << 4) + n][(g << 3)];
            const bf16x8 k1 = *(const bf16x8*)&Ks[kcol0 + (t << 4) + n][32 + (g << 3)];
#pragma unroll
            for (int qt = 0; qt < 2; ++qt) {
                f32x4 a = {0.f, 0.f, 0.f, 0.f};
                a = __builtin_amdgcn_mfma_f32_16x16x32_bf16(qf[qt][0], k0, a, 0, 0, 0);
                a = __builtin_amdgcn_mfma_f32_16x16x32_bf16(qf[qt][1], k1, a, 0, 0, 0);
                S[qt][t] = a;
            }
        }

        if (jt >= (qb << 1)) {
#pragma unroll
            for (int qt = 0; qt < 2; ++qt)
#pragma unroll
                for (int t = 0; t < 2; ++t)
#pragma unroll
                    for (int reg = 0; reg < 4; ++reg) {
                        const int kg = (jt << 6) + kcol0 + (t << 4) + n;
                        const int qgl = qr0 + qrow0 + (qt << 4) + (g << 2) + reg;
                        if (kg > qgl) S[qt][t][reg] = -INFINITY;
                    }
        }

#pragma unroll
        for (int qt = 0; qt < 2; ++qt)
#pragma unroll
            for (int t = 0; t < 2; ++t)
#pragma unroll
                for (int reg = 0; reg < 4; ++reg)
                    QPs[qrow0 + (qt << 4) + (g << 2) + reg]
                       [kcol0 + (((t << 4) + n) ^ (g << 3))] =
                        (__bf16)__expf(S[qt][t][reg]);

        bf16x8 vf[4];
#pragma unroll
        for (int dt = 0; dt < 4; ++dt) {
            const int vr = (dt << 4) + n;
            const bf16x4 lo = *(const bf16x4*)&Vt[vr][kcol0 + (g << 3)];
            const bf16x4 hi = *(const bf16x4*)&Vt[vr][kcol0 + (g << 3) + 4];
#pragma unroll
            for (int j = 0; j < 4; ++j) { vf[dt][j] = lo[j]; vf[dt][4 + j] = hi[j]; }
        }

#pragma unroll
        for (int qt = 0; qt < 2; ++qt) {
            const bf16x8 p = *(const bf16x8*)&QPs[qrow0 + (qt << 4) + n][kcol0 + sw];
            L[qt] = __builtin_amdgcn_mfma_f32_16x16x32_bf16(p, ones, L[qt], 0, 0, 0);
#pragma unroll
            for (int dt = 0; dt < 4; ++dt)
                O[qt][dt] = __builtin_amdgcn_mfma_f32_16x16x32_bf16(p, vf[dt], O[qt][dt], 0, 0, 0);
        }
    }

    __syncthreads();
    float* red = (float*)SMEM;
    if (kh == 1) {
#pragma unroll
        for (int qt = 0; qt < 2; ++qt)
#pragma unroll
            for (int reg = 0; reg < 4; ++reg) {
                const int qlx = qrow0 + (qt << 4) + (g << 2) + reg;
#pragma unroll
                for (int dt = 0; dt < 4; ++dt)
                    red[qlx * 64 + (dt << 4) + n] = O[qt][dt][reg];
                if (n == 0) red[8192 + qlx] = L[qt][reg];
            }
    }
    __syncthreads();
    if (kh == 0) {
#pragma unroll
        for (int qt = 0; qt < 2; ++qt)
#pragma unroll
            for (int reg = 0; reg < 4; ++reg) {
                const int qlx = qrow0 + (qt << 4) + (g << 2) + reg;
                const float inv = 1.0f / (L[qt][reg] + red[8192 + qlx]);
                const size_t row = (size_t)b * NT + qr0 + qlx;
#pragma unroll
                for (int dt = 0; dt < 4; ++dt)
                    out[row * NC + col + (dt << 4) + n] =
                        (__bf16)((O[qt][dt][reg] + red[qlx * 64 + (dt << 4) + n]) * inv);
            }
    }
}

// ---------------------------------------------------------------------------
extern "C" void kernel_launch(void* const* d_in, const int* in_sizes, int n_in,
                              void* d_out, int out_size, void* d_ws, size_t ws_size,
                              hipStream_t stream)
{
    const float* x     = (const float*)d_in[0];
    const float* Wqkv  = (const float*)d_in[1];
    const float* bqkv  = (const float*)d_in[2];
    const float* Wproj = (const float*)d_in[3];
    const float* bproj = (const float*)d_in[4];
    float* out = (float*)d_out;

    // workspace carve (bytes)
    char* ws = (char*)d_ws;
    __bf16* qkvb   = (__bf16*)(ws);                    // 24.0 MB
    __bf16* attb   = (__bf16*)(ws + 25165824);         //  8.0 MB
    __bf16* wqkvt  = (__bf16*)(ws + 33554432);         //  1.5 MB
    __bf16* wprojt = (__bf16*)(ws + 35127296);         //  0.5 MB

    // 4 launches total
    prep_kernel<<<dim3(256), dim3(256), 0, stream>>>(Wqkv, Wproj, wqkvt, wprojt);

    gemm_bf16_kernel<true><<<dim3(N3C / 128, (NB * NT) / 128), dim3(256), 0, stream>>>(
        x, wqkvt, bqkv, qkvb, NB * NT, N3C, NC, 1);

    attn_kernel<<<dim3(NT / 128, NB * NH), dim3(512), 0, stream>>>(qkvb, attb);

    gemm_bf16_kernel<false><<<dim3(NC / 128, (NB * NT) / 128), dim3(256), 0, stream>>>(
        attb, wprojt, bproj, out, NB * NT, NC, NC, 0);
}

// Round 11
// 196.977 us; speedup vs baseline: 1.0499x; 1.0499x over previous
//
#include <hip/hip_runtime.h>
#include <math.h>

#define NB 2
#define NT 4096
#define NC 512
#define NH 8
#define ND 64
#define N3C (3*NC)

typedef __attribute__((ext_vector_type(8))) __bf16 bf16x8;
typedef __attribute__((ext_vector_type(4))) __bf16 bf16x4;
typedef __attribute__((ext_vector_type(4))) float  f32x4;

// async 16B/lane global->LDS DMA; lds base must be wave-uniform
__device__ __forceinline__ void load_lds16(const __bf16* g, __bf16* l) {
    __builtin_amdgcn_global_load_lds(
        (const __attribute__((address_space(1))) void*)g,
        (__attribute__((address_space(3))) void*)l, 16, 0, 0);
}

// ---------------------------------------------------------------------------
// fp32 -> bf16 elementwise (x)
// ---------------------------------------------------------------------------
__global__ __launch_bounds__(256) void cvt_bf16_kernel(
    const float* __restrict__ x, __bf16* __restrict__ xb, int n)
{
    const int i = (blockIdx.x * 256 + threadIdx.x) << 3;
    if (i < n) {
        float4 a = *(const float4*)(x + i);
        float4 b = *(const float4*)(x + i + 4);
        bf16x8 o;
        o[0] = (__bf16)a.x; o[1] = (__bf16)a.y; o[2] = (__bf16)a.z; o[3] = (__bf16)a.w;
        o[4] = (__bf16)b.x; o[5] = (__bf16)b.y; o[6] = (__bf16)b.z; o[7] = (__bf16)b.w;
        *(bf16x8*)(xb + i) = o;
    }
}

// ---------------------------------------------------------------------------
// prep: W[K][N] fp32 -> Wt[N][K] bf16, both weights in one launch
// ---------------------------------------------------------------------------
__global__ __launch_bounds__(256) void prep_kernel(
    const float* __restrict__ Wqkv, const float* __restrict__ Wproj,
    __bf16* __restrict__ wqkvt, __bf16* __restrict__ wprojt)
{
    __shared__ float T[64][65];
    int id = blockIdx.x;
    const float* W; __bf16* Wt; int N, n0, k0;
    if (id < 192) { W = Wqkv;  Wt = wqkvt;  N = N3C; n0 = (id % 24) << 6; k0 = (id / 24) << 6; }
    else { id -= 192; W = Wproj; Wt = wprojt; N = NC;  n0 = (id & 7) << 6;  k0 = (id >> 3) << 6; }
    const int K = NC;

    const int tx = threadIdx.x & 15, ty = threadIdx.x >> 4;
#pragma unroll
    for (int i = 0; i < 4; ++i) {
        const int r = ty + (i << 4);
        float4 v = *(const float4*)(W + (size_t)(k0 + r) * N + n0 + (tx << 2));
        T[r][(tx << 2) + 0] = v.x;
        T[r][(tx << 2) + 1] = v.y;
        T[r][(tx << 2) + 2] = v.z;
        T[r][(tx << 2) + 3] = v.w;
    }
    __syncthreads();
#pragma unroll
    for (int i = 0; i < 4; ++i) {
        const int nr = ty + (i << 4);
        bf16x4 o;
        o[0] = (__bf16)T[(tx << 2) + 0][nr];
        o[1] = (__bf16)T[(tx << 2) + 1][nr];
        o[2] = (__bf16)T[(tx << 2) + 2][nr];
        o[3] = (__bf16)T[(tx << 2) + 3][nr];
        *(bf16x4*)(Wt + (size_t)(n0 + nr) * K + k0 + (tx << 2)) = o;
    }
}

// ---------------------------------------------------------------------------
// bf16 MFMA GEMM with global_load_lds staging. C = A @ Bt^T + bias.
// Tile BM x 128, BK=64. XOR-swizzled LDS granules: element A[r][k] (granule
// kg=k/8) lives at LDS row r, phys granule kg^(r&7) -> conflict-free b128
// reads AND a valid lane->base+i*16 DMA layout (swizzle folded into the
// per-lane GLOBAL address instead of the LDS address).
// MFMA k-order identical to R10 -> bit-identical results.
// ---------------------------------------------------------------------------
template<int BM>
__global__ __launch_bounds__(256) void gemm_glds_kernel(
    const __bf16* __restrict__ A, const __bf16* __restrict__ Bt,
    const float* __restrict__ bias, void* __restrict__ Cout,
    int M, int N, int K, int out_bf16)
{
    constexpr int IT = BM / 32;              // i-tiles per wave (4 or 2)
    constexpr int AI = BM / 32;              // A DMA instrs per wave (4 or 2)
    __shared__ __align__(16) __bf16 As[BM * 64];
    __shared__ __align__(16) __bf16 Bs[128 * 64];

    const int tid  = threadIdx.x;
    const int w    = tid >> 6, lane = tid & 63;
    const int g    = lane >> 4, n = lane & 15;
    const int n7   = n & 7;
    const int wr   = (w >> 1) * (BM / 2);
    const int wc   = (w & 1) << 6;
    const int m0   = blockIdx.y * BM, n0 = blockIdx.x << 7;

    // DMA descriptors: instr q of wave w covers granules G = wbase + q*64 + lane
    const __bf16* ag[AI]; __bf16* al[AI];
#pragma unroll
    for (int q = 0; q < AI; ++q) {
        const int G = w * (BM * 2) + q * 64 + lane;      // BM*8/4 granules per wave
        const int r = G >> 3, pg = G & 7, kg = pg ^ (r & 7);
        ag[q] = A + (size_t)(m0 + r) * K + (kg << 3);
        al[q] = As + ((w * (BM * 2) + q * 64) << 3);     // wave-uniform base
    }
    const __bf16* bg[4]; __bf16* bl[4];
#pragma unroll
    for (int q = 0; q < 4; ++q) {
        const int G = w * 256 + q * 64 + lane;
        const int r = G >> 3, pg = G & 7, kg = pg ^ (r & 7);
        bg[q] = Bt + (size_t)(n0 + r) * K + (kg << 3);
        bl[q] = Bs + ((w * 256 + q * 64) << 3);
    }

    f32x4 acc[IT][4];
#pragma unroll
    for (int i = 0; i < IT; ++i)
#pragma unroll
        for (int j = 0; j < 4; ++j) acc[i][j] = (f32x4){0.f, 0.f, 0.f, 0.f};

    const int ksteps = K >> 6;
    for (int ks = 0; ks < ksteps; ++ks) {
        __syncthreads();                       // all waves done reading prev tile
        const int ko = ks << 6;
#pragma unroll
        for (int q = 0; q < AI; ++q) load_lds16(ag[q] + ko, al[q]);
#pragma unroll
        for (int q = 0; q < 4;  ++q) load_lds16(bg[q] + ko, bl[q]);
        __syncthreads();                       // vmcnt(0) drained before barrier

#pragma unroll
        for (int s = 0; s < 2; ++s) {
            bf16x8 af[IT], bf[4];
#pragma unroll
            for (int i = 0; i < IT; ++i) {
                const int row = wr + (i << 4) + n;
                af[i] = *(const bf16x8*)&As[(row << 6) + ((((s << 2) + g) ^ n7) << 3)];
            }
#pragma unroll
            for (int j = 0; j < 4; ++j) {
                const int row = wc + (j << 4) + n;
                bf[j] = *(const bf16x8*)&Bs[(row << 6) + ((((s << 2) + g) ^ n7) << 3)];
            }
#pragma unroll
            for (int i = 0; i < IT; ++i)
#pragma unroll
                for (int j = 0; j < 4; ++j)
                    acc[i][j] = __builtin_amdgcn_mfma_f32_16x16x32_bf16(af[i], bf[j], acc[i][j], 0, 0, 0);
        }
    }

#pragma unroll
    for (int j = 0; j < 4; ++j) {
        const int colg = n0 + wc + (j << 4) + n;
        const float bb = bias[colg];
#pragma unroll
        for (int i = 0; i < IT; ++i) {
#pragma unroll
            for (int reg = 0; reg < 4; ++reg) {
                const int rowg = m0 + wr + (i << 4) + (g << 2) + reg;
                const float v = acc[i][j][reg] + bb;
                if (out_bf16)
                    ((__bf16*)Cout)[(size_t)rowg * N + colg] = (__bf16)v;
                else
                    ((float*)Cout)[(size_t)rowg * N + colg] = v;
            }
        }
    }
}

// ---------------------------------------------------------------------------
// Causal flash attention (R9/R10 structure, unchanged)
// ---------------------------------------------------------------------------
__global__ __launch_bounds__(512) void attn_kernel(
    const __bf16* __restrict__ qkv, __bf16* __restrict__ out)
{
    __shared__ __align__(16) unsigned char SMEM[36352];
    __bf16 (*QPs)[72] = (__bf16(*)[72])SMEM;
    __bf16 (*Ks)[72]  = (__bf16(*)[72])(SMEM + 18432);
    __bf16 (*Vt)[68]  = (__bf16(*)[68])(SMEM + 27648);

    const int tid  = threadIdx.x;
    const int xi   = blockIdx.x;
    const int bh   = blockIdx.y;
    const int qb   = (bh < 8) ? (31 - xi) : xi;
    const int b    = bh >> 3, h = bh & 7;
    const int qr0  = qb << 7;
    const size_t base = (size_t)b * NT * N3C;
    const int col  = h * ND;

    const int w    = tid >> 6;
    const int lane = tid & 63;
    const int g    = lane >> 4;
    const int n    = lane & 15;
    const int qg   = w >> 1;
    const int kh   = w & 1;
    const int qrow0 = qg << 5;
    const int kcol0 = kh << 5;
    const int sw   = (g ^ (n >> 2)) << 3;

    const int kr = tid >> 3;
    const int kc = (tid & 7) << 3;
    const int vd = lane;
    const int vk = w << 2;

    const __bf16* kptr = qkv + base + NC + col + kc;
    const __bf16* vptr = qkv + base + 2 * NC + col + vd;

#pragma unroll
    for (int i = 0; i < 2; ++i) {
        const int r = kr + (i << 6);
        bf16x8 v = *(const bf16x8*)(qkv + base + (size_t)(qr0 + r) * N3C + col + kc);
        bf16x8 q;
#pragma unroll
        for (int j = 0; j < 8; ++j) q[j] = (__bf16)(0.125f * (float)v[j]);
        *(bf16x8*)&QPs[r][kc] = q;
    }
    __syncthreads();

    bf16x8 qf[2][2];
#pragma unroll
    for (int qt = 0; qt < 2; ++qt)
#pragma unroll
        for (int hh = 0; hh < 2; ++hh)
            qf[qt][hh] = *(const bf16x8*)&QPs[qrow0 + (qt << 4) + n][(hh << 5) + (g << 3)];

    bf16x8 ones;
#pragma unroll
    for (int j = 0; j < 8; ++j) ones[j] = (__bf16)1.0f;

    f32x4 O[2][4];
#pragma unroll
    for (int qt = 0; qt < 2; ++qt)
#pragma unroll
        for (int dt = 0; dt < 4; ++dt) O[qt][dt] = (f32x4){0.f, 0.f, 0.f, 0.f};
    f32x4 L[2] = {{0.f,0.f,0.f,0.f},{0.f,0.f,0.f,0.f}};

    bf16x8 kreg = *(const bf16x8*)(kptr + (size_t)kr * N3C);
    __bf16 vreg[8];
#pragma unroll
    for (int j = 0; j < 4; ++j) {
        vreg[j]     = vptr[(size_t)(vk + j) * N3C];
        vreg[4 + j] = vptr[(size_t)(vk + 32 + j) * N3C];
    }

    const int ntiles = (qb << 1) + 2;
    for (int jt = 0; jt < ntiles; ++jt) {
        __syncthreads();
        *(bf16x8*)&Ks[kr][kc] = kreg;
        {
            bf16x4 va, vb;
#pragma unroll
            for (int j = 0; j < 4; ++j) { va[j] = vreg[j]; vb[j] = vreg[4 + j]; }
            *(bf16x4*)&Vt[vd][vk]      = va;
            *(bf16x4*)&Vt[vd][vk + 32] = vb;
        }
        __syncthreads();

        if (jt + 1 < ntiles) {
            const int kr1 = (jt + 1) << 6;
            kreg = *(const bf16x8*)(kptr + (size_t)(kr1 + kr) * N3C);
#pragma unroll
            for (int j = 0; j < 4; ++j) {
                vreg[j]     = vptr[(size_t)(kr1 + vk + j) * N3C];
                vreg[4 + j] = vptr[(size_t)(kr1 + vk + 32 + j) * N3C];
            }
        }

        f32x4 S[2][2];
#pragma unroll
        for (int t = 0; t < 2; ++t) {
            const bf16x8 k0 = *(const bf16x8*)&Ks[kcol0 + (t << 4) + n][(g << 3)];
            const bf16x8 k1 = *(const bf16x8*)&Ks[kcol0 + (t << 4) + n][32 + (g << 3)];
#pragma unroll
            for (int qt = 0; qt < 2; ++qt) {
                f32x4 a = {0.f, 0.f, 0.f, 0.f};
                a = __builtin_amdgcn_mfma_f32_16x16x32_bf16(qf[qt][0], k0, a, 0, 0, 0);
                a = __builtin_amdgcn_mfma_f32_16x16x32_bf16(qf[qt][1], k1, a, 0, 0, 0);
                S[qt][t] = a;
            }
        }

        if (jt >= (qb << 1)) {
#pragma unroll
            for (int qt = 0; qt < 2; ++qt)
#pragma unroll
                for (int t = 0; t < 2; ++t)
#pragma unroll
                    for (int reg = 0; reg < 4; ++reg) {
                        const int kg = (jt << 6) + kcol0 + (t << 4) + n;
                        const int qgl = qr0 + qrow0 + (qt << 4) + (g << 2) + reg;
                        if (kg > qgl) S[qt][t][reg] = -INFINITY;
                    }
        }

#pragma unroll
        for (int qt = 0; qt < 2; ++qt)
#pragma unroll
            for (int t = 0; t < 2; ++t)
#pragma unroll
                for (int reg = 0; reg < 4; ++reg)
                    QPs[qrow0 + (qt << 4) + (g << 2) + reg]
                       [kcol0 + (((t << 4) + n) ^ (g << 3))] =
                        (__bf16)__expf(S[qt][t][reg]);

        bf16x8 vf[4];
#pragma unroll
        for (int dt = 0; dt < 4; ++dt) {
            const int vr = (dt << 4) + n;
            const bf16x4 lo = *(const bf16x4*)&Vt[vr][kcol0 + (g << 3)];
            const bf16x4 hi = *(const bf16x4*)&Vt[vr][kcol0 + (g << 3) + 4];
#pragma unroll
            for (int j = 0; j < 4; ++j) { vf[dt][j] = lo[j]; vf[dt][4 + j] = hi[j]; }
        }

#pragma unroll
        for (int qt = 0; qt < 2; ++qt) {
            const bf16x8 p = *(const bf16x8*)&QPs[qrow0 + (qt << 4) + n][kcol0 + sw];
            L[qt] = __builtin_amdgcn_mfma_f32_16x16x32_bf16(p, ones, L[qt], 0, 0, 0);
#pragma unroll
            for (int dt = 0; dt < 4; ++dt)
                O[qt][dt] = __builtin_amdgcn_mfma_f32_16x16x32_bf16(p, vf[dt], O[qt][dt], 0, 0, 0);
        }
    }

    __syncthreads();
    float* red = (float*)SMEM;
    if (kh == 1) {
#pragma unroll
        for (int qt = 0; qt < 2; ++qt)
#pragma unroll
            for (int reg = 0; reg < 4; ++reg) {
                const int qlx = qrow0 + (qt << 4) + (g << 2) + reg;
#pragma unroll
                for (int dt = 0; dt < 4; ++dt)
                    red[qlx * 64 + (dt << 4) + n] = O[qt][dt][reg];
                if (n == 0) red[8192 + qlx] = L[qt][reg];
            }
    }
    __syncthreads();
    if (kh == 0) {
#pragma unroll
        for (int qt = 0; qt < 2; ++qt)
#pragma unroll
            for (int reg = 0; reg < 4; ++reg) {
                const int qlx = qrow0 + (qt << 4) + (g << 2) + reg;
                const float inv = 1.0f / (L[qt][reg] + red[8192 + qlx]);
                const size_t row = (size_t)b * NT + qr0 + qlx;
#pragma unroll
                for (int dt = 0; dt < 4; ++dt)
                    out[row * NC + col + (dt << 4) + n] =
                        (__bf16)((O[qt][dt][reg] + red[qlx * 64 + (dt << 4) + n]) * inv);
            }
    }
}

// ---------------------------------------------------------------------------
extern "C" void kernel_launch(void* const* d_in, const int* in_sizes, int n_in,
                              void* d_out, int out_size, void* d_ws, size_t ws_size,
                              hipStream_t stream)
{
    const float* x     = (const float*)d_in[0];
    const float* Wqkv  = (const float*)d_in[1];
    const float* bqkv  = (const float*)d_in[2];
    const float* Wproj = (const float*)d_in[3];
    const float* bproj = (const float*)d_in[4];
    float* out = (float*)d_out;

    // workspace carve (bytes)
    char* ws = (char*)d_ws;
    __bf16* xb     = (__bf16*)(ws);                    //  8.0 MB
    __bf16* qkvb   = (__bf16*)(ws + 8388608);          // 24.0 MB
    __bf16* attb   = (__bf16*)(ws + 33554432);         //  8.0 MB
    __bf16* wqkvt  = (__bf16*)(ws + 41943040);         //  1.5 MB
    __bf16* wprojt = (__bf16*)(ws + 43515904);         //  0.5 MB

    cvt_bf16_kernel<<<dim3(2048), dim3(256), 0, stream>>>(x, xb, NB * NT * NC);
    prep_kernel<<<dim3(256), dim3(256), 0, stream>>>(Wqkv, Wproj, wqkvt, wprojt);

    gemm_glds_kernel<128><<<dim3(N3C / 128, (NB * NT) / 128), dim3(256), 0, stream>>>(
        xb, wqkvt, bqkv, qkvb, NB * NT, N3C, NC, 1);

    attn_kernel<<<dim3(NT / 128, NB * NH), dim3(512), 0, stream>>>(qkvb, attb);

    gemm_glds_kernel<64><<<dim3(NC / 128, (NB * NT) / 64), dim3(256), 0, stream>>>(
        attb, wprojt, bproj, out, NB * NT, NC, NC, 0);
}